// Round 14
// baseline (171.685 us; speedup 1.0000x reference)
//
#include <hip/hip_runtime.h>
#include <hip/hip_bf16.h>

typedef __hip_bfloat16 bf16;
typedef __attribute__((ext_vector_type(8))) short bf16x8v;
typedef __attribute__((ext_vector_type(4))) float f32x4v;

#define N_NODES 10000
#define DMODEL  128
#define NHEADS  8
#define CHEAD   16

// Floats are f32 (verified round 4). k/v/A-side intermediates bf16
// (error budget: thr 0.204 >> observed 0.031).
// R12 lesson: software grid barriers across XCDs are catastrophic — keep
// inter-phase sync at launch boundaries.
// Softmax: logits (q.k)/4 have |p| <~ 10 << 88 (f32 exp overflow), so raw
// exp (shift-invariant; clamp@60 dead insurance) == reference softmax.
// R13 lesson: exp-chain removal alone gained ~0 — attn is MLP-bound; this
// round doubles in-flight work (16 edges/iter).

__device__ __forceinline__ float bf2f(unsigned u) {
    union { unsigned i; float f; } c; c.i = u << 16; return c.f;
}
__device__ __forceinline__ unsigned short f2bf_bits(float f) {
    bf16 b = __float2bfloat16(f);
    return *(unsigned short*)&b;
}

// ---------------------------------------------------------------------------
// Fused QKVS GEMM via bf16 MFMA + (layer 0 only) CSR build.
// grid = (8, 157), block = 256 = 4 waves. Fragment layouts (HW-verified):
// A/B [m|n = lane&15][k=(lane>>4)*8+j]; C/D col=lane&15, row=(lane>>4)*4+reg.
// CSR: per-block dtype self-detect (int64 => odd 32-bit words all zero in
// probe window); graph = 2-hop closure of undirected+self-loops =>
// symmetric & src-sorted => row d of src-sorted list = in-neighbors(d).
// ---------------------------------------------------------------------------
__global__ __launch_bounds__(256) void gemm_qkvs(
    const void* __restrict__ Ain, int a_is_bf16,
    const float* __restrict__ Wq, const float* __restrict__ Wk,
    const float* __restrict__ Wv, const float* __restrict__ Ws,
    const float* __restrict__ bq, const float* __restrict__ bk,
    const float* __restrict__ bv, const float* __restrict__ bs,
    int welem, int belem,
    float* __restrict__ qo, bf16* __restrict__ ko, bf16* __restrict__ vo,
    float* __restrict__ hso,
    const int* __restrict__ aw, int E,           // E>0 => also build CSR
    int* __restrict__ rowptr, int* __restrict__ nbr)
{
    __shared__ unsigned short As[64][136];   // [m][k]
    __shared__ unsigned short Bs[128][68];   // [k][n]
    __shared__ int nz;

    const int tid = threadIdx.x;

    if (E > 0) {
        if (tid == 0) nz = 0;
        __syncthreads();
        int W = 4096;
        if (W > 2 * E) W = 2 * E;
        int any = 0;
        for (int w = 1 + 2 * tid; w < W; w += 2 * (int)blockDim.x)
            any |= aw[w];
        if (any) atomicOr(&nz, 1);
        __syncthreads();
        const int is64 = (nz == 0);

        const int gid = (blockIdx.y * gridDim.x + blockIdx.x) * blockDim.x
                      + tid;
        const int gtot = gridDim.x * gridDim.y * blockDim.x;
        if (gid == 0) rowptr[N_NODES] = E;
        for (int e = gid; e < E; e += gtot) {
            int s  = is64 ? aw[2 * e] : aw[e];
            if (s < 0) s = 0;
            if (s >= N_NODES) s = N_NODES - 1;
            int sp = (e == 0) ? -1 : (is64 ? aw[2 * (e - 1)] : aw[e - 1]);
            for (int r = sp + 1; r <= s; ++r) rowptr[r] = e;  // ~1 iter
            if (e == E - 1)
                for (int r = s + 1; r < N_NODES; ++r) rowptr[r] = E;
            int d = is64 ? aw[2 * (E + e)] : aw[E + e];
            if (d < 0) d = 0;
            if (d >= N_NODES) d = N_NODES - 1;
            nbr[e] = d;
        }
        __syncthreads();
    }

    const int cb    = blockIdx.x;
    const int row0  = blockIdx.y * 64;
    const int mat   = cb >> 1;               // 0=q 1=k 2=v 3=s
    const float* W    = (mat == 0) ? Wq : (mat == 1) ? Wk
                      : (mat == 2) ? Wv : Ws;
    const float* bias = (mat == 0) ? bq : (mat == 1) ? bk
                      : (mat == 2) ? bv : bs;
    const int colW0 = (cb & 1) * 64;

    if (a_is_bf16) {
        const unsigned short* A = (const unsigned short*)Ain;
        #pragma unroll
        for (int i = 0; i < 4; ++i) {
            int idx = tid + i * 256;
            int row = idx >> 4, k8 = idx & 15;
            int grow = row0 + row;
            uint4 u = make_uint4(0u, 0u, 0u, 0u);
            if (grow < N_NODES)
                u = *(const uint4*)&A[grow * DMODEL + k8 * 8];
            *(uint4*)&As[row][k8 * 8] = u;
        }
    } else {
        const float* A = (const float*)Ain;
        #pragma unroll
        for (int i = 0; i < 8; ++i) {
            int idx = tid + i * 256;
            int row = idx >> 5, k4 = idx & 31;
            int grow = row0 + row;
            float4 av = make_float4(0.f, 0.f, 0.f, 0.f);
            if (grow < N_NODES)
                av = *(const float4*)&A[grow * DMODEL + k4 * 4];
            ushort4 p;
            p.x = f2bf_bits(av.x); p.y = f2bf_bits(av.y);
            p.z = f2bf_bits(av.z); p.w = f2bf_bits(av.w);
            *(ushort4*)&As[row][k4 * 4] = p;
        }
    }
    #pragma unroll
    for (int i = 0; i < 8; ++i) {
        int idx = tid + i * 256;
        int kk = idx >> 4, n4 = idx & 15;
        float4 wv = *(const float4*)&W[welem + kk * DMODEL + colW0 + n4 * 4];
        ushort4 p;
        p.x = f2bf_bits(wv.x); p.y = f2bf_bits(wv.y);
        p.z = f2bf_bits(wv.z); p.w = f2bf_bits(wv.w);
        *(ushort4*)&Bs[kk][n4 * 4] = p;
    }
    __syncthreads();

    const int wave = tid >> 6, lane = tid & 63;
    const int ln = lane & 15, quad = lane >> 4;
    const int ncol = wave * 16 + ln;

    f32x4v acc[4];
    #pragma unroll
    for (int mt = 0; mt < 4; ++mt) acc[mt] = (f32x4v){0.f, 0.f, 0.f, 0.f};

    #pragma unroll
    for (int ks = 0; ks < 4; ++ks) {
        const int kb = ks * 32 + quad * 8;
        bf16x8v bfv;
        #pragma unroll
        for (int j = 0; j < 8; ++j) bfv[j] = (short)Bs[kb + j][ncol];
        #pragma unroll
        for (int mt = 0; mt < 4; ++mt) {
            bf16x8v afv = *(const bf16x8v*)&As[mt * 16 + ln][kb];
            acc[mt] = __builtin_amdgcn_mfma_f32_16x16x32_bf16(
                afv, bfv, acc[mt], 0, 0, 0);
        }
    }

    const float bcol = bias[belem + colW0 + ncol];
    #pragma unroll
    for (int mt = 0; mt < 4; ++mt) {
        #pragma unroll
        for (int r = 0; r < 4; ++r) {
            int row = row0 + mt * 16 + quad * 4 + r;
            if (row >= N_NODES) continue;
            float val = acc[mt][r] + bcol;
            int elo = row * DMODEL + colW0 + ncol;
            if (mat == 0)      qo[elo] = val;
            else if (mat == 3) hso[elo] = val;
            else if (mat == 1) ko[elo] = __float2bfloat16(val);
            else               vo[elo] = __float2bfloat16(val);
        }
    }
}

// ---------------------------------------------------------------------------
// Wave-autonomous sparse attention, 16 edges in flight per iteration
// (two independent 8-edge sub-groups — raw exp makes groups independent).
// One wave per node (grid-stride), no __syncthreads, no LDS. Lanes =
// 8 edge-slots x 8 heads. Per iter: 2 k-row fragments/lane (64 B), 16
// coalesced v-row reads, 2 dots, 2 exps — all loads issue before any use.
// ---------------------------------------------------------------------------
__global__ __launch_bounds__(256) void attn_fused(
    const float* __restrict__ q, const bf16* __restrict__ k,
    const bf16* __restrict__ v, const float* __restrict__ hs,
    const float* __restrict__ hin,
    const int* __restrict__ rowptr, const int* __restrict__ nbr,
    float* __restrict__ out, unsigned short* __restrict__ outb,
    int relu_flag)
{
    const int wid = blockIdx.x * 4 + (threadIdx.x >> 6);
    const int nWaves = gridDim.x * 4;
    const int l = threadIdx.x & 63;
    const int h = l & 7, slot = l >> 3;
    const int hc = l >> 3;

    for (int d = wid; d < N_NODES; d += nWaves) {
        float qf[16];
        const float* qp = q + d * DMODEL + h * CHEAD;
        #pragma unroll
        for (int i = 0; i < 4; ++i) {
            float4 t4 = *(const float4*)(qp + i * 4);
            qf[i * 4 + 0] = t4.x; qf[i * 4 + 1] = t4.y;
            qf[i * 4 + 2] = t4.z; qf[i * 4 + 3] = t4.w;
        }

        const int e0 = rowptr[d], e1 = rowptr[d + 1];
        float zacc = 0.f;
        float2 acc = make_float2(0.f, 0.f);

        for (int base = e0; base < e1; base += 16) {
            const int iA = base + slot, iB = base + 8 + slot;
            const bool padA = !(iA < e1), padB = !(iB < e1);
            const int sA = padA ? d : nbr[iA];
            const int sB = padB ? d : nbr[iB];

            // issue all 4 k-fragment loads up front
            const uint4* kpA = (const uint4*)(k + sA * DMODEL + h * CHEAD);
            const uint4* kpB = (const uint4*)(k + sB * DMODEL + h * CHEAD);
            uint4 ka0 = kpA[0], ka1 = kpA[1];
            uint4 kb0 = kpB[0], kb1 = kpB[1];

            // broadcast row ids, issue all 16 v loads
            int seA[8], seB[8];
            #pragma unroll
            for (int e = 0; e < 8; ++e) {
                seA[e] = __shfl(sA, e * 8);
                seB[e] = __shfl(sB, e * 8);
            }
            unsigned uvA[8], uvB[8];
            #pragma unroll
            for (int e = 0; e < 8; ++e) {
                uvA[e] = *(const unsigned*)(v + seA[e] * DMODEL + 2 * l);
                uvB[e] = *(const unsigned*)(v + seB[e] * DMODEL + 2 * l);
            }

            // two independent dots
            const unsigned* a0 = (const unsigned*)&ka0;
            const unsigned* a1 = (const unsigned*)&ka1;
            const unsigned* b0 = (const unsigned*)&kb0;
            const unsigned* b1 = (const unsigned*)&kb1;
            float dA = 0.f, dB = 0.f;
            #pragma unroll
            for (int w = 0; w < 4; ++w) {
                dA += qf[w * 2 + 0] * bf2f(a0[w] & 0xffffu);
                dA += qf[w * 2 + 1] * bf2f(a0[w] >> 16);
                dB += qf[w * 2 + 0] * bf2f(b0[w] & 0xffffu);
                dB += qf[w * 2 + 1] * bf2f(b0[w] >> 16);
            }
            #pragma unroll
            for (int w = 0; w < 4; ++w) {
                dA += qf[8 + w * 2 + 0] * bf2f(a1[w] & 0xffffu);
                dA += qf[8 + w * 2 + 1] * bf2f(a1[w] >> 16);
                dB += qf[8 + w * 2 + 0] * bf2f(b1[w] & 0xffffu);
                dB += qf[8 + w * 2 + 1] * bf2f(b1[w] >> 16);
            }
            float pA = padA ? -3.0e38f : fminf(dA * 0.25f, 60.f);
            float pB = padB ? -3.0e38f : fminf(dB * 0.25f, 60.f);
            float peA = __expf(pA);               // 0 for pad lanes
            float peB = __expf(pB);
            zacc += peA + peB;

            float peeA[8], peeB[8];
            #pragma unroll
            for (int e = 0; e < 8; ++e) {
                peeA[e] = __shfl(peA, e * 8 + hc);
                peeB[e] = __shfl(peB, e * 8 + hc);
            }
            #pragma unroll
            for (int e = 0; e < 8; ++e) {
                acc.x += peeA[e] * bf2f(uvA[e] & 0xffffu);
                acc.y += peeA[e] * bf2f(uvA[e] >> 16);
                acc.x += peeB[e] * bf2f(uvB[e] & 0xffffu);
                acc.y += peeB[e] * bf2f(uvB[e] >> 16);
            }
        }

        float z = zacc;
        z += __shfl_xor(z, 8);
        z += __shfl_xor(z, 16);
        z += __shfl_xor(z, 32);
        float zh = __shfl(z, hc);
        float inv = (zh > 0.f) ? (1.f / zh) : 0.f;

        int idx = d * DMODEL + 2 * l;
        float2 hsv = *(const float2*)(hs + idx);
        float2 hiv = *(const float2*)(hin + idx);
        float2 o;
        o.x = acc.x * inv + hsv.x + hiv.x;
        o.y = acc.y * inv + hsv.y + hiv.y;
        if (relu_flag) { o.x = fmaxf(o.x, 0.f); o.y = fmaxf(o.y, 0.f); }
        *(float2*)(out + idx) = o;
        if (outb) {
            unsigned pk = f2bf_bits(o.x) | ((unsigned)f2bf_bits(o.y) << 16);
            *(unsigned*)&outb[idx] = pk;
        }
    }
}

// ---------------------------------------------------------------------------
extern "C" void kernel_launch(void* const* d_in, const int* in_sizes, int n_in,
                              void* d_out, int out_size, void* d_ws, size_t ws_size,
                              hipStream_t stream) {
    const float* x  = (const float*)d_in[0];
    const float* Wq = (const float*)d_in[1];
    const float* bq = (const float*)d_in[2];
    const float* Wk = (const float*)d_in[3];
    const float* bk = (const float*)d_in[4];
    const float* Wv = (const float*)d_in[5];
    const float* bv = (const float*)d_in[6];
    const float* Ws = (const float*)d_in[7];
    const float* bs = (const float*)d_in[8];
    const int*   aw = (const int*)d_in[9];
    const int E = in_sizes[9] / 2;

    char* ws = (char*)d_ws;
    size_t off = 0;
    float* qb = (float*)(ws + off);  off += (size_t)N_NODES * DMODEL * 4;
    bf16*  kb = (bf16*)(ws + off);   off += (size_t)N_NODES * DMODEL * 2;
    bf16*  vb = (bf16*)(ws + off);   off += (size_t)N_NODES * DMODEL * 2;
    float* hsb = (float*)(ws + off); off += (size_t)N_NODES * DMODEL * 4;
    float* h1 = (float*)(ws + off);  off += (size_t)N_NODES * DMODEL * 4;
    unsigned short* h1b = (unsigned short*)(ws + off);
    off += (size_t)N_NODES * DMODEL * 2;
    int* rowptr = (int*)(ws + off);  off += ((size_t)N_NODES + 2) * 4;
    int* nbr    = (int*)(ws + off);  off += (size_t)E * 4;

    dim3 ggrid(8, (N_NODES + 63) / 64);
    const int ablocks = (N_NODES + 3) / 4;   // 4 waves per 256-thr block

    // layer 0 GEMM + CSR build (fused; CSR consumed only after this kernel)
    gemm_qkvs<<<ggrid, 256, 0, stream>>>(x, 0, Wq, Wk, Wv, Ws,
                                         bq, bk, bv, bs, 0, 0,
                                         qb, kb, vb, hsb, aw, E, rowptr, nbr);
    // layer 0 attention (ReLU): hin = x, out = h1 (+bf16 mirror)
    attn_fused<<<ablocks, 256, 0, stream>>>(qb, kb, vb, hsb, x, rowptr, nbr,
                                            h1, h1b, 1);
    // layer 1 GEMM (A = h1 bf16 mirror)
    gemm_qkvs<<<ggrid, 256, 0, stream>>>(h1b, 1, Wq, Wk, Wv, Ws,
                                         bq, bk, bv, bs,
                                         DMODEL * DMODEL, DMODEL,
                                         qb, kb, vb, hsb, aw, 0, rowptr, nbr);
    // layer 1 attention (no ReLU) -> d_out (f32)
    attn_fused<<<ablocks, 256, 0, stream>>>(qb, kb, vb, hsb, h1, rowptr, nbr,
                                            (float*)d_out, (unsigned short*)0,
                                            0);
}

// Round 15
// 163.297 us; speedup vs baseline: 1.0514x; 1.0514x over previous
//
#include <hip/hip_runtime.h>
#include <hip/hip_bf16.h>

typedef __hip_bfloat16 bf16;
typedef __attribute__((ext_vector_type(8))) short bf16x8v;
typedef __attribute__((ext_vector_type(4))) float f32x4v;

#define N_NODES 10000
#define DMODEL  128
#define NHEADS  8
#define CHEAD   16

// Floats are f32 (verified round 4). k/v/A-side intermediates bf16
// (error budget: thr 0.204 >> observed 0.031).
// R12 lesson: software grid barriers across XCDs are catastrophic — keep
// inter-phase sync at launch boundaries.
// R14 lesson: 16-edge unroll regressed (VGPR/occupancy cliff) — 8 edges/iter
// with k-prefetch is the local optimum for this gather pattern.
// Softmax: logits (q.k)/4 have |p| <~ 10 << 88 (f32 exp overflow), so raw
// exp (shift-invariant; clamp@60 dead insurance) == reference softmax.

__device__ __forceinline__ float bf2f(unsigned u) {
    union { unsigned i; float f; } c; c.i = u << 16; return c.f;
}
__device__ __forceinline__ unsigned short f2bf_bits(float f) {
    bf16 b = __float2bfloat16(f);
    return *(unsigned short*)&b;
}

// ---------------------------------------------------------------------------
// Fused QKVS GEMM via bf16 MFMA + (layer 0 only) CSR build.
// grid = (8, 157), block = 256 = 4 waves. Fragment layouts (HW-verified):
// A/B [m|n = lane&15][k=(lane>>4)*8+j]; C/D col=lane&15, row=(lane>>4)*4+reg.
// CSR: per-block dtype self-detect (int64 => odd 32-bit words all zero in
// probe window); graph = 2-hop closure of undirected+self-loops =>
// symmetric & src-sorted => row d of src-sorted list = in-neighbors(d).
// ---------------------------------------------------------------------------
__global__ __launch_bounds__(256) void gemm_qkvs(
    const void* __restrict__ Ain, int a_is_bf16,
    const float* __restrict__ Wq, const float* __restrict__ Wk,
    const float* __restrict__ Wv, const float* __restrict__ Ws,
    const float* __restrict__ bq, const float* __restrict__ bk,
    const float* __restrict__ bv, const float* __restrict__ bs,
    int welem, int belem,
    float* __restrict__ qo, bf16* __restrict__ ko, bf16* __restrict__ vo,
    float* __restrict__ hso,
    const int* __restrict__ aw, int E,           // E>0 => also build CSR
    int* __restrict__ rowptr, int* __restrict__ nbr)
{
    __shared__ unsigned short As[64][136];   // [m][k]
    __shared__ unsigned short Bs[128][68];   // [k][n]
    __shared__ int nz;

    const int tid = threadIdx.x;

    if (E > 0) {
        if (tid == 0) nz = 0;
        __syncthreads();
        int W = 4096;
        if (W > 2 * E) W = 2 * E;
        int any = 0;
        for (int w = 1 + 2 * tid; w < W; w += 2 * (int)blockDim.x)
            any |= aw[w];
        if (any) atomicOr(&nz, 1);
        __syncthreads();
        const int is64 = (nz == 0);

        const int gid = (blockIdx.y * gridDim.x + blockIdx.x) * blockDim.x
                      + tid;
        const int gtot = gridDim.x * gridDim.y * blockDim.x;
        if (gid == 0) rowptr[N_NODES] = E;
        for (int e = gid; e < E; e += gtot) {
            int s  = is64 ? aw[2 * e] : aw[e];
            if (s < 0) s = 0;
            if (s >= N_NODES) s = N_NODES - 1;
            int sp = (e == 0) ? -1 : (is64 ? aw[2 * (e - 1)] : aw[e - 1]);
            for (int r = sp + 1; r <= s; ++r) rowptr[r] = e;  // ~1 iter
            if (e == E - 1)
                for (int r = s + 1; r < N_NODES; ++r) rowptr[r] = E;
            int d = is64 ? aw[2 * (E + e)] : aw[E + e];
            if (d < 0) d = 0;
            if (d >= N_NODES) d = N_NODES - 1;
            nbr[e] = d;
        }
        __syncthreads();
    }

    const int cb    = blockIdx.x;
    const int row0  = blockIdx.y * 64;
    const int mat   = cb >> 1;               // 0=q 1=k 2=v 3=s
    const float* W    = (mat == 0) ? Wq : (mat == 1) ? Wk
                      : (mat == 2) ? Wv : Ws;
    const float* bias = (mat == 0) ? bq : (mat == 1) ? bk
                      : (mat == 2) ? bv : bs;
    const int colW0 = (cb & 1) * 64;

    if (a_is_bf16) {
        const unsigned short* A = (const unsigned short*)Ain;
        #pragma unroll
        for (int i = 0; i < 4; ++i) {        // A: 64 rows x 128 k (copy)
            int idx = tid + i * 256;
            int row = idx >> 4, k8 = idx & 15;
            int grow = row0 + row;
            uint4 u = make_uint4(0u, 0u, 0u, 0u);
            if (grow < N_NODES)
                u = *(const uint4*)&A[grow * DMODEL + k8 * 8];
            *(uint4*)&As[row][k8 * 8] = u;
        }
    } else {
        const float* A = (const float*)Ain;
        #pragma unroll
        for (int i = 0; i < 8; ++i) {        // A: f32 -> bf16 staging
            int idx = tid + i * 256;
            int row = idx >> 5, k4 = idx & 31;
            int grow = row0 + row;
            float4 av = make_float4(0.f, 0.f, 0.f, 0.f);
            if (grow < N_NODES)
                av = *(const float4*)&A[grow * DMODEL + k4 * 4];
            ushort4 p;
            p.x = f2bf_bits(av.x); p.y = f2bf_bits(av.y);
            p.z = f2bf_bits(av.z); p.w = f2bf_bits(av.w);
            *(ushort4*)&As[row][k4 * 4] = p;
        }
    }
    #pragma unroll
    for (int i = 0; i < 8; ++i) {            // B: 128 k x 64 n, f32->bf16
        int idx = tid + i * 256;
        int kk = idx >> 4, n4 = idx & 15;
        float4 wv = *(const float4*)&W[welem + kk * DMODEL + colW0 + n4 * 4];
        ushort4 p;
        p.x = f2bf_bits(wv.x); p.y = f2bf_bits(wv.y);
        p.z = f2bf_bits(wv.z); p.w = f2bf_bits(wv.w);
        *(ushort4*)&Bs[kk][n4 * 4] = p;
    }
    __syncthreads();

    const int wave = tid >> 6, lane = tid & 63;
    const int ln = lane & 15, quad = lane >> 4;
    const int ncol = wave * 16 + ln;

    f32x4v acc[4];
    #pragma unroll
    for (int mt = 0; mt < 4; ++mt) acc[mt] = (f32x4v){0.f, 0.f, 0.f, 0.f};

    #pragma unroll
    for (int ks = 0; ks < 4; ++ks) {
        const int kb = ks * 32 + quad * 8;
        bf16x8v bfv;
        #pragma unroll
        for (int j = 0; j < 8; ++j) bfv[j] = (short)Bs[kb + j][ncol];
        #pragma unroll
        for (int mt = 0; mt < 4; ++mt) {
            bf16x8v afv = *(const bf16x8v*)&As[mt * 16 + ln][kb];
            acc[mt] = __builtin_amdgcn_mfma_f32_16x16x32_bf16(
                afv, bfv, acc[mt], 0, 0, 0);
        }
    }

    const float bcol = bias[belem + colW0 + ncol];
    #pragma unroll
    for (int mt = 0; mt < 4; ++mt) {
        #pragma unroll
        for (int r = 0; r < 4; ++r) {
            int row = row0 + mt * 16 + quad * 4 + r;
            if (row >= N_NODES) continue;
            float val = acc[mt][r] + bcol;
            int elo = row * DMODEL + colW0 + ncol;
            if (mat == 0)      qo[elo] = val;
            else if (mat == 3) hso[elo] = val;
            else if (mat == 1) ko[elo] = __float2bfloat16(val);
            else               vo[elo] = __float2bfloat16(val);
        }
    }
}

// ---------------------------------------------------------------------------
// Wave-autonomous sparse attention + epilogue, NO online-max rescaling
// (raw exp is exact softmax by shift-invariance; clamp@60 is dead insurance).
// One wave per node (grid-stride), no __syncthreads, no LDS. Lanes =
// 8 edge-slots x 8 heads; k/v addresses depend only on nbr[], so next
// group's k and current group's v issue before the dot — groups are
// independent (only acc/z adds carried). 8 edges/iter (R14: 16 regressed).
// ---------------------------------------------------------------------------
__global__ __launch_bounds__(256) void attn_fused(
    const float* __restrict__ q, const bf16* __restrict__ k,
    const bf16* __restrict__ v, const float* __restrict__ hs,
    const float* __restrict__ hin,
    const int* __restrict__ rowptr, const int* __restrict__ nbr,
    float* __restrict__ out, unsigned short* __restrict__ outb,
    int relu_flag)
{
    const int wid = blockIdx.x * 4 + (threadIdx.x >> 6);
    const int nWaves = gridDim.x * 4;
    const int l = threadIdx.x & 63;
    const int h = l & 7, slot = l >> 3;
    const int hc = l >> 3;

    for (int d = wid; d < N_NODES; d += nWaves) {
        float qf[16];
        const float* qp = q + d * DMODEL + h * CHEAD;
        #pragma unroll
        for (int i = 0; i < 4; ++i) {
            float4 t4 = *(const float4*)(qp + i * 4);
            qf[i * 4 + 0] = t4.x; qf[i * 4 + 1] = t4.y;
            qf[i * 4 + 2] = t4.z; qf[i * 4 + 3] = t4.w;
        }

        const int e0 = rowptr[d], e1 = rowptr[d + 1];
        float zacc = 0.f;
        float2 acc = make_float2(0.f, 0.f);

        int eg = e0 + slot;
        bool pad_cur = !(eg < e1);
        int s_cur = pad_cur ? d : nbr[eg];
        const uint4* kp0 = (const uint4*)(k + s_cur * DMODEL + h * CHEAD);
        uint4 kc0 = kp0[0], kc1 = kp0[1];

        for (int base = e0; base < e1; base += 8) {
            int en = base + 8 + slot;
            bool pad_nxt = !(en < e1);
            int s_nxt = pad_nxt ? d : nbr[en];
            const uint4* kpn = (const uint4*)(k + s_nxt * DMODEL + h * CHEAD);
            uint4 kn0 = kpn[0], kn1 = kpn[1];

            int se[8];
            #pragma unroll
            for (int e = 0; e < 8; ++e) se[e] = __shfl(s_cur, e * 8);
            unsigned uv[8];
            #pragma unroll
            for (int e = 0; e < 8; ++e)
                uv[e] = *(const unsigned*)(v + se[e] * DMODEL + 2 * l);

            const unsigned* w0 = (const unsigned*)&kc0;
            const unsigned* w1 = (const unsigned*)&kc1;
            float dot = 0.f;
            #pragma unroll
            for (int w = 0; w < 4; ++w) {
                dot += qf[w * 2 + 0] * bf2f(w0[w] & 0xffffu);
                dot += qf[w * 2 + 1] * bf2f(w0[w] >> 16);
            }
            #pragma unroll
            for (int w = 0; w < 4; ++w) {
                dot += qf[8 + w * 2 + 0] * bf2f(w1[w] & 0xffffu);
                dot += qf[8 + w * 2 + 1] * bf2f(w1[w] >> 16);
            }
            float p = pad_cur ? -3.0e38f : fminf(dot * 0.25f, 60.f);
            float pe = __expf(p);                 // 0 for pad lanes
            zacc += pe;

            float pee[8];
            #pragma unroll
            for (int e = 0; e < 8; ++e) pee[e] = __shfl(pe, e * 8 + hc);
            #pragma unroll
            for (int e = 0; e < 8; ++e) {
                acc.x += pee[e] * bf2f(uv[e] & 0xffffu);
                acc.y += pee[e] * bf2f(uv[e] >> 16);
            }

            kc0 = kn0; kc1 = kn1; s_cur = s_nxt; pad_cur = pad_nxt;
        }

        float z = zacc;
        z += __shfl_xor(z, 8);
        z += __shfl_xor(z, 16);
        z += __shfl_xor(z, 32);
        float zh = __shfl(z, hc);
        float inv = (zh > 0.f) ? (1.f / zh) : 0.f;

        int idx = d * DMODEL + 2 * l;
        float2 hsv = *(const float2*)(hs + idx);
        float2 hiv = *(const float2*)(hin + idx);
        float2 o;
        o.x = acc.x * inv + hsv.x + hiv.x;
        o.y = acc.y * inv + hsv.y + hiv.y;
        if (relu_flag) { o.x = fmaxf(o.x, 0.f); o.y = fmaxf(o.y, 0.f); }
        *(float2*)(out + idx) = o;
        if (outb) {
            unsigned pk = f2bf_bits(o.x) | ((unsigned)f2bf_bits(o.y) << 16);
            *(unsigned*)&outb[idx] = pk;
        }
    }
}

// ---------------------------------------------------------------------------
extern "C" void kernel_launch(void* const* d_in, const int* in_sizes, int n_in,
                              void* d_out, int out_size, void* d_ws, size_t ws_size,
                              hipStream_t stream) {
    const float* x  = (const float*)d_in[0];
    const float* Wq = (const float*)d_in[1];
    const float* bq = (const float*)d_in[2];
    const float* Wk = (const float*)d_in[3];
    const float* bk = (const float*)d_in[4];
    const float* Wv = (const float*)d_in[5];
    const float* bv = (const float*)d_in[6];
    const float* Ws = (const float*)d_in[7];
    const float* bs = (const float*)d_in[8];
    const int*   aw = (const int*)d_in[9];
    const int E = in_sizes[9] / 2;

    char* ws = (char*)d_ws;
    size_t off = 0;
    float* qb = (float*)(ws + off);  off += (size_t)N_NODES * DMODEL * 4;
    bf16*  kb = (bf16*)(ws + off);   off += (size_t)N_NODES * DMODEL * 2;
    bf16*  vb = (bf16*)(ws + off);   off += (size_t)N_NODES * DMODEL * 2;
    float* hsb = (float*)(ws + off); off += (size_t)N_NODES * DMODEL * 4;
    float* h1 = (float*)(ws + off);  off += (size_t)N_NODES * DMODEL * 4;
    unsigned short* h1b = (unsigned short*)(ws + off);
    off += (size_t)N_NODES * DMODEL * 2;
    int* rowptr = (int*)(ws + off);  off += ((size_t)N_NODES + 2) * 4;
    int* nbr    = (int*)(ws + off);  off += (size_t)E * 4;

    dim3 ggrid(8, (N_NODES + 63) / 64);
    const int ablocks = (N_NODES + 3) / 4;   // 4 waves per 256-thr block

    // layer 0 GEMM + CSR build (fused; CSR consumed only after this kernel)
    gemm_qkvs<<<ggrid, 256, 0, stream>>>(x, 0, Wq, Wk, Wv, Ws,
                                         bq, bk, bv, bs, 0, 0,
                                         qb, kb, vb, hsb, aw, E, rowptr, nbr);
    // layer 0 attention (ReLU): hin = x, out = h1 (+bf16 mirror)
    attn_fused<<<ablocks, 256, 0, stream>>>(qb, kb, vb, hsb, x, rowptr, nbr,
                                            h1, h1b, 1);
    // layer 1 GEMM (A = h1 bf16 mirror)
    gemm_qkvs<<<ggrid, 256, 0, stream>>>(h1b, 1, Wq, Wk, Wv, Ws,
                                         bq, bk, bv, bs,
                                         DMODEL * DMODEL, DMODEL,
                                         qb, kb, vb, hsb, aw, 0, rowptr, nbr);
    // layer 1 attention (no ReLU) -> d_out (f32)
    attn_fused<<<ablocks, 256, 0, stream>>>(qb, kb, vb, hsb, h1, rowptr, nbr,
                                            (float*)d_out, (unsigned short*)0,
                                            0);
}